// Round 18
// baseline (80.561 us; speedup 1.0000x reference)
//
#include <hip/hip_runtime.h>
#include <hip/hip_fp16.h>
#include <math.h>

// ---- problem constants (match reference) ----
#define NCOLS   407
#define RAD_OFF 87
#define ANG_OFF 151
#define T1      3072          // items per sort tile
#define KPT     (T1 / 256)    // 12 items per thread
#define WB      32            // atoms per bucket (bucket = atom>>5)
#define MAXBKT  640           // max buckets (n_atoms <= 20480)
#define CAPF    1792          // fixed per-bucket region capacity
#define C2      (CAPF / 256)  // 7 items per thread in pass2B

// shiftR[r] = 0.8 + r*0.275  (r=0..15)
// shiftA[a] = 0.8 + a*0.675  (a=0..3)
// shiftZ[z] = pi/8 + z*pi/4  (z=0..3)

typedef __attribute__((ext_vector_type(8))) _Float16 f16x8;
typedef __attribute__((ext_vector_type(4))) float    f32x4;

static __device__ inline unsigned pack2(float a, float b) {
    __half2 h = __floats2half2_rn(a, b);
    return *reinterpret_cast<unsigned*>(&h);
}
static __device__ inline float2 unpack2(unsigned u) {
    __half2 h = *reinterpret_cast<__half2*>(&u);
    return __half22float2(h);
}

// ============ ze: ang edata + rad edata + cursor zeroing (all streaming) ============
// blocks [0,nbe): angular edata; [nbe, nbe+nbr): radial edata; last block: cursors
__global__ __launch_bounds__(256) void ze_kernel(const float* __restrict__ ang_dist,
                                                 const float* __restrict__ ang_sw,
                                                 const int* __restrict__ ang_edge_dst,
                                                 const float* __restrict__ dist,
                                                 const float* __restrict__ sw,
                                                 const int* __restrict__ edst,
                                                 const int* __restrict__ species,
                                                 const float4* __restrict__ valence,
                                                 uint4* __restrict__ edata,
                                                 uint4* __restrict__ rad_edata,
                                                 int* __restrict__ cursors,
                                                 int n_ang_edges, int n_edges,
                                                 int nbe, int nbr) {
    int bid = blockIdx.x;
    int t = threadIdx.x;
    if (bid == nbe + nbr) {
        for (int i = t; i < 2 * MAXBKT; i += 256) cursors[i] = 0;
        return;
    }
    if (bid < nbe) {
        int i = bid * 2560 + t;
        #pragma unroll
        for (int k = 0; k < 10; ++k, i += 256) {
            if (i < n_ang_edges) {
                float4 v = valence[species[ang_edge_dst[i]]];
                uint4 r;
                r.x = __float_as_uint(ang_dist[i]);
                r.y = __float_as_uint(ang_sw[i]);
                r.z = pack2(v.x, v.y);
                r.w = pack2(v.z, v.w);
                edata[i] = r;
            }
        }
    } else {
        int i = (bid - nbe) * 2560 + t;
        #pragma unroll
        for (int k = 0; k < 10; ++k, i += 256) {
            if (i < n_edges) {
                float d  = dist[i];
                float ps = 0.25f * sw[i];
                float4 v = valence[species[edst[i]]];
                uint4 r;
                r.x = __float_as_uint(d);
                r.y = pack2(ps * v.x, ps * v.y);
                r.z = pack2(ps * v.z, ps * v.w);
                r.w = 0u;
                rad_edata[i] = r;
            }
        }
    }
}

// ============ pass1: records + LDS bucket-reorder + cursor-claimed COALESCED store ============
// records: radial {d, pv01, pv23, atom}; angular {e1, e2, ang, atom}
__global__ __launch_bounds__(256) void pass1_kernel(
    const uint4* __restrict__ rad_edata,
    const int* __restrict__ esrc,
    const float* __restrict__ ang_angles,
    const int* __restrict__ psrc, const int* __restrict__ pdst,
    const int* __restrict__ central,
    int* __restrict__ cur_rad, int* __restrict__ cur_ang,
    uint4* __restrict__ arr_rad, uint4* __restrict__ arr_ang,
    int n_edges, int n_pairs, int nbkt, int nt_rad)
{
    __shared__ uint4 buf[T1];        // 48 KB
    __shared__ int   lh[MAXBKT];     // counts -> packed local bases
    __shared__ int   gb[MAXBKT];     // global positions (region base + claimed run)
    __shared__ int   wtot[4];

    int bid = blockIdx.x;
    int t = threadIdx.x;
    int is_ang = bid >= nt_rad;
    const int* key = is_ang ? central : esrc;
    int* cursor = is_ang ? cur_ang : cur_rad;
    int n   = is_ang ? n_pairs : n_edges;
    int off = (is_ang ? bid - nt_rad : bid) * T1;
    int cnt = min(T1, n - off);
    uint4* arr = is_ang ? arr_ang : arr_rad;

    for (int b = t; b < nbkt; b += 256) lh[b] = 0;
    __syncthreads();

    // loop 1: per-item rank within (tile, bucket)
    int meta[KPT];                   // atom<<12 | rank
    #pragma unroll
    for (int k = 0; k < KPT; ++k) {
        int i = off + k * 256 + t;
        meta[k] = -1;
        if (i < n) {
            int atom = key[i];
            int r = atomicAdd(&lh[atom >> 5], 1);
            meta[k] = (atom << 12) | r;
        }
    }
    __syncthreads();

    // scan + claim: per-wave shuffle scan over bin ranges (2 barriers total)
    {
        int w = t >> 6, lane = t & 63;
        int W4  = (nbkt + 3) >> 2;               // bins per wave
        int wlo = w * W4;
        int whi = min(wlo + W4, nbkt);
        int b0 = wlo + lane * 3;                 // 3 bins per lane (64*3=192 >= W4)
        int c0 = (b0     < whi) ? lh[b0]     : 0;
        int c1 = (b0 + 1 < whi) ? lh[b0 + 1] : 0;
        int c2 = (b0 + 2 < whi) ? lh[b0 + 2] : 0;
        int lsum = c0 + c1 + c2;
        int s = lsum;
        #pragma unroll
        for (int o = 1; o < 64; o <<= 1) {
            int u = __shfl_up(s, o, 64);
            if (lane >= o) s += u;
        }
        int excl = s - lsum;                     // wave-local exclusive base
        // claim global runs (independent of packing)
        if (c0) gb[b0]     = b0       * CAPF + atomicAdd(&cursor[b0],     c0);
        if (c1) gb[b0 + 1] = (b0 + 1) * CAPF + atomicAdd(&cursor[b0 + 1], c1);
        if (c2) gb[b0 + 2] = (b0 + 2) * CAPF + atomicAdd(&cursor[b0 + 2], c2);
        // wave-local packed bases
        if (b0     < whi) lh[b0]     = excl;
        if (b0 + 1 < whi) lh[b0 + 1] = excl + c0;
        if (b0 + 2 < whi) lh[b0 + 2] = excl + c0 + c1;
        if (lane == 63) wtot[w] = s;
        __syncthreads();
        int wbase = 0;
        for (int ww = 0; ww < w; ++ww) wbase += wtot[ww];
        if (wbase) {
            if (b0     < whi) lh[b0]     += wbase;
            if (b0 + 1 < whi) lh[b0 + 1] += wbase;
            if (b0 + 2 < whi) lh[b0 + 2] += wbase;
        }
        __syncthreads();
    }

    // loop 2: build records, place into LDS at bucket-packed position
    #pragma unroll
    for (int k = 0; k < KPT; ++k) {
        if (meta[k] < 0) continue;
        int i = off + k * 256 + t;
        int atom = meta[k] >> 12, r = meta[k] & 4095;
        int b = atom >> 5;
        uint4 rec;
        if (!is_ang) {
            uint4 e = rad_edata[i];              // one coalesced 16B load
            rec.x = e.x; rec.y = e.y; rec.z = e.z;
            rec.w = (unsigned)atom;
        } else {
            rec.x = (unsigned)psrc[i];
            rec.y = (unsigned)pdst[i];
            rec.z = __float_as_uint(ang_angles[i]);
            rec.w = (unsigned)atom;
        }
        buf[lh[b] + r] = rec;
    }
    __syncthreads();

    // loop 3: coalesced writer; dst recomputed from record atom
    #pragma unroll
    for (int k = 0; k < KPT; ++k) {
        int j = k * 256 + t;
        if (j < cnt) {
            uint4 r = buf[j];
            int b = (int)(r.w >> 5);
            int gpos = gb[b] + (j - lh[b]);           // consecutive within run
            if (gpos < (b + 1) * CAPF) arr[gpos] = r; // overflow drop (P~0)
        }
    }
}

// ============ pass2B: per-bucket LDS sort + per-atom MFMA compute + onehot ============
// blocks [0,nbkt): radial buckets; [nbkt,2nbkt): angular buckets
__global__ __launch_bounds__(256) void pass2B_kernel(
    const uint4* __restrict__ arr_rad, const uint4* __restrict__ arr_ang,
    const uint4* __restrict__ edata,
    const int* __restrict__ cur_rad, const int* __restrict__ cur_ang,
    const int* __restrict__ species,
    float* __restrict__ out, int nbkt, int n_atoms)
{
    __shared__ uint4 buf[CAPF];               // 28.7 KB records
    __shared__ unsigned short ord[CAPF];      //  3.5 KB permutation
    __shared__ int lh[WB];
    __shared__ int sA[WB + 1];
    __shared__ uint4 stg[4][256];             // 16 KB per-wave MFMA staging (angular)

    int bid = blockIdx.x;
    int t = threadIdx.x;
    int g = bid >= nbkt;
    int b = g ? bid - nbkt : bid;
    int lo  = b * CAPF;
    int cnt = min(g ? cur_ang[b] : cur_rad[b], CAPF);
    const uint4* arr = g ? arr_ang : arr_rad;
    int loA = b << 5;

    // ---- load + count + rank in ONE pass (ranks in static regs) ----
    if (t < WB) lh[t] = 0;
    __syncthreads();
    int myar[C2];
    #pragma unroll
    for (int c = 0; c < C2; ++c) {
        int j = c * 256 + t;
        myar[c] = -1;
        if (j < cnt) {
            uint4 r = arr[lo + j];
            buf[j] = r;
            int a = (int)r.w - loA;
            if ((unsigned)a < WB) {
                int rk = atomicAdd(&lh[a], 1);
                myar[c] = (a << 12) | rk;
            }
        }
    }
    __syncthreads();
    // wave 0: 32-bin shuffle scan
    if (t < 64) {
        int v = (t < WB) ? lh[t] : 0;
        int s = v;
        #pragma unroll
        for (int o = 1; o < WB; o <<= 1) {
            int u = __shfl_up(s, o, 64);
            if (t >= o) s += u;
        }
        if (t < WB) sA[t + 1] = s;
        if (t == 0) sA[0] = 0;
    }
    __syncthreads();
    #pragma unroll
    for (int c = 0; c < C2; ++c) {
        if (myar[c] >= 0) {
            int j = c * 256 + t;
            ord[sA[myar[c] >> 12] + (myar[c] & 4095)] = (unsigned short)j;
        }
    }
    __syncthreads();

    int w    = t >> 6;
    int lane = t & 63;
    int m  = lane & 15;
    int g4 = lane >> 4;

    if (g) {
        // ---------------- angular: DENSE staging, masked-MFMA per atom ----------------
        // wave w owns atoms [w*8, w*8+8); stages its whole ord-range densely (all
        // lanes active), consumes per 32-row chunk with row-interval-masked A-frag.
        const _Float16* hl = (const _Float16*)stg[w];
        int aw0 = w * 8;
        int R0 = sA[aw0], R1 = sA[aw0 + 8];
        int cur = aw0;                       // current atom (wave-uniform)
        f32x4 acc = {0.f, 0.f, 0.f, 0.f};

        for (int base = R0; base < R1; base += 64) {
            int idx = base + lane;
            unsigned q[16];
            if (idx < R1) {
                uint4 pr = buf[ord[idx]];                 // LDS gather
                int e1 = (int)pr.x;
                int e2 = (int)pr.y;
                float ang = __uint_as_float(pr.z);
                uint4 r1 = edata[e1];                     // L2-hot gathers
                uint4 r2 = edata[e2];
                float d12 = 0.5f * (__uint_as_float(r1.x) + __uint_as_float(r2.x));
                float swp = 2.0f * __uint_as_float(r1.y) * __uint_as_float(r2.y);
                float2 v1a = unpack2(r1.z), v1b = unpack2(r1.w);
                float2 v2a = unpack2(r2.z), v2b = unpack2(r2.w);
                float vp[4] = {v1a.x + v2a.x, v1a.y + v2a.y, v1b.x + v2b.x, v1b.y + v2b.y};
                float vm[4] = {v1a.x * v2a.x, v1a.y * v2a.y, v1b.x * v2b.x, v1b.y * v2b.y};

                float sa, ca;
                __sincosf(ang, &sa, &ca);
                const float czv[4] = { 0.92387953f,  0.38268343f, -0.38268343f, -0.92387953f };
                const float szv[4] = { 0.38268343f,  0.92387953f,  0.92387953f,  0.38268343f };
                float f1v[4];
                #pragma unroll
                for (int z = 0; z < 4; ++z) {
                    float y = 0.5f + 0.5f * (ca * czv[z] + sa * szv[z]);
                    float y2 = y * y, y4 = y2 * y2, y8 = y4 * y4, y16 = y8 * y8;
                    f1v[z] = y16 * y16;
                }
                float f2sv[4];
                #pragma unroll
                for (int aa = 0; aa < 4; ++aa) {
                    float x = d12 - (0.8f + 0.675f * (float)aa);
                    f2sv[aa] = swp * __expf(-8.0f * x * x);
                }
                #pragma unroll
                for (int aa = 0; aa < 4; ++aa) {
                    q[aa * 2 + 0] = pack2(f2sv[aa] * f1v[0], f2sv[aa] * f1v[1]);
                    q[aa * 2 + 1] = pack2(f2sv[aa] * f1v[2], f2sv[aa] * f1v[3]);
                }
                #pragma unroll
                for (int i2 = 0; i2 < 4; ++i2) {
                    q[8 + i2 * 2 + 0] = pack2(vp[i2] * vm[0], vp[i2] * vm[1]);
                    q[8 + i2 * 2 + 1] = pack2(vp[i2] * vm[2], vp[i2] * vm[3]);
                }
            } else {
                #pragma unroll
                for (int k = 0; k < 16; ++k) q[k] = 0u;   // zero-pad tail
            }
            stg[w][lane * 4 + 0] = make_uint4(q[0],  q[1],  q[2],  q[3]);
            stg[w][lane * 4 + 1] = make_uint4(q[4],  q[5],  q[6],  q[7]);
            stg[w][lane * 4 + 2] = make_uint4(q[8],  q[9],  q[10], q[11]);
            stg[w][lane * 4 + 3] = make_uint4(q[12], q[13], q[14], q[15]);
            asm volatile("s_waitcnt lgkmcnt(0)" ::: "memory");

            // consume the two 32-row chunks of this staged block
            #pragma unroll
            for (int c = 0; c < 2; ++c) {
                int cbase = base + c * 32;
                if (cbase >= R1) break;
                while (cur < aw0 + 8) {
                    int abeg = sA[cur], aend = sA[cur + 1];
                    int lo_r = max(abeg, cbase) - cbase;
                    int hi_r = min(aend, cbase + 32) - cbase;
                    if (hi_r > lo_r) {
                        f16x8 wf, uf;
                        #pragma unroll
                        for (int i = 0; i < 8; ++i) {
                            int rr  = (g4 << 3) + i;          // row within chunk (k-slot)
                            int row = c * 32 + rr;            // row within staged block
                            bool live = (rr >= lo_r && rr < hi_r);
                            wf[i] = live ? hl[row * 32 + m] : (_Float16)0.0f;
                            uf[i] = hl[row * 32 + 16 + m];    // wf=0 masks contribution
                        }
                        acc = __builtin_amdgcn_mfma_f32_16x16x32_f16(wf, uf, acc, 0, 0, 0);
                    }
                    if (aend <= cbase + 32) {
                        // atom complete: flush (C/D: col=lane&15, row=(lane>>4)*4+reg)
                        int atom = loA + cur;
                        if (atom < n_atoms) {
                            float* orow = out + (size_t)atom * NCOLS + ANG_OFF;
                            #pragma unroll
                            for (int r = 0; r < 4; ++r)
                                orow[(g4 * 4 + r) * 16 + m] = acc[r];
                        }
                        acc = (f32x4){0.f, 0.f, 0.f, 0.f};
                        ++cur;
                    } else {
                        break;   // atom extends into next chunk
                    }
                }
            }
            asm volatile("s_waitcnt lgkmcnt(0)" ::: "memory");
        }
        // trailing atoms with no pairs (or R0==R1 entirely)
        while (cur < aw0 + 8) {
            int atom = loA + cur;
            if (atom < n_atoms) {
                float* orow = out + (size_t)atom * NCOLS + ANG_OFF;
                #pragma unroll
                for (int r = 0; r < 4; ++r)
                    orow[(g4 * 4 + r) * 16 + m] = 0.0f;
            }
            ++cur;
        }
        return;
    }

    // ---------------- radial: 4 waves x 8 atoms + onehot ----------------
    const _Float16* hl = (const _Float16*)buf;     // rec = 8 halves: [d_lo,d_hi,pv0..3,atom]
    const float*    fl = (const float*)buf;
    float shiftm = 0.8f + 0.275f * (float)m;
    for (int ai = 0; ai < 8; ++ai) {
        int a = w * 8 + ai;
        int atom = loA + a;
        if (atom >= n_atoms) break;
        int beg = sA[a], end = sA[a + 1];
        f32x4 acc = {0.f, 0.f, 0.f, 0.f};

        for (int base = beg; base < end; base += 64) {
            int cnt2 = min(64, end - base);
            {
                f16x8 wf, uf;
                #pragma unroll
                for (int i = 0; i < 8; ++i) {
                    int k = (g4 << 3) + i;                // edges 0..31
                    int live = (k < cnt2);
                    int o = live ? (int)ord[base + k] : 0;
                    float d = fl[o * 4];
                    float x = d - shiftm;
                    float e = __expf(-16.0f * x * x);
                    wf[i] = live ? (_Float16)e : (_Float16)0.0f;
                    uf[i] = (live && m < 4) ? hl[o * 8 + 2 + m] : (_Float16)0.0f;
                }
                acc = __builtin_amdgcn_mfma_f32_16x16x32_f16(wf, uf, acc, 0, 0, 0);
            }
            if (cnt2 > 32) {
                f16x8 wf, uf;
                #pragma unroll
                for (int i = 0; i < 8; ++i) {
                    int k = 32 + (g4 << 3) + i;           // edges 32..63
                    int live = (k < cnt2);
                    int o = live ? (int)ord[base + k] : 0;
                    float d = fl[o * 4];
                    float x = d - shiftm;
                    float e = __expf(-16.0f * x * x);
                    wf[i] = live ? (_Float16)e : (_Float16)0.0f;
                    uf[i] = (live && m < 4) ? hl[o * 8 + 2 + m] : (_Float16)0.0f;
                }
                acc = __builtin_amdgcn_mfma_f32_16x16x32_f16(wf, uf, acc, 0, 0, 0);
            }
        }
        if (m < 4) {
            size_t rowbase = (size_t)atom * NCOLS;
            #pragma unroll
            for (int r = 0; r < 4; ++r)
                out[rowbase + RAD_OFF + (g4 * 4 + r) * 4 + m] = acc[r];
        }
    }

    // onehot for this bucket's 32 atoms
    for (int idx2 = t; idx2 < WB * 87; idx2 += 256) {
        int a = idx2 / 87, c = idx2 - a * 87;
        int atom = loA + a;
        if (atom < n_atoms)
            out[(size_t)atom * NCOLS + c] = (c == species[atom]) ? 1.0f : 0.0f;
    }
}

extern "C" void kernel_launch(void* const* d_in, const int* in_sizes, int n_in,
                              void* d_out, int out_size, void* d_ws, size_t ws_size,
                              hipStream_t stream) {
    const int*   species      = (const int*)  d_in[0];
    const float* distances    = (const float*)d_in[1];
    const float* switch_      = (const float*)d_in[2];
    const int*   edge_src     = (const int*)  d_in[3];
    const int*   edge_dst     = (const int*)  d_in[4];
    const float* ang_angles   = (const float*)d_in[5];
    const float* ang_dist     = (const float*)d_in[6];
    const float* ang_switch   = (const float*)d_in[7];
    const int*   ang_edge_dst = (const int*)  d_in[8];
    const int*   angle_src    = (const int*)  d_in[9];
    const int*   angle_dst    = (const int*)  d_in[10];
    const int*   central_atom = (const int*)  d_in[11];
    const float4* valence     = (const float4*)d_in[12];

    float* out = (float*)d_out;

    const int n_atoms     = in_sizes[0];
    const int n_edges     = in_sizes[1];
    const int n_ang_edges = in_sizes[6];
    const int n_pairs     = in_sizes[5];

    const int nbkt   = (n_atoms + WB - 1) / WB;       // 625 (<= MAXBKT)
    const int nt_rad = (n_edges + T1 - 1) / T1;       // 209
    const int nt_ang = (n_pairs + T1 - 1) / T1;       // 183

    // ---- workspace layout (16B-aligned), total ~= 48.7 MB ----
    char* ws = (char*)d_ws;
    size_t off = 0;
    auto alloc = [&](size_t bytes) -> void* {
        void* p = ws + off;
        off = (off + bytes + 15) & ~(size_t)15;
        return p;
    };
    uint4* arr_rad   = (uint4*)alloc((size_t)nbkt * CAPF * 16);      // 17.92 MB
    uint4* arr_ang   = (uint4*)alloc((size_t)nbkt * CAPF * 16);      // 17.92 MB
    uint4* rad_edata = (uint4*)alloc((size_t)n_edges * 16);          // 10.24 MB
    uint4* edata     = (uint4*)alloc((size_t)n_ang_edges * 16);      //  2.56 MB
    int*   cursors   = (int*)  alloc((size_t)2 * MAXBKT * sizeof(int));
    int* cur_rad = cursors;
    int* cur_ang = cursors + MAXBKT;

    int nbe = (n_ang_edges + 2559) / 2560;
    int nbr = (n_edges + 2559) / 2560;
    ze_kernel<<<nbe + nbr + 1, 256, 0, stream>>>(
        ang_dist, ang_switch, ang_edge_dst, distances, switch_, edge_dst,
        species, valence, edata, rad_edata, cursors,
        n_ang_edges, n_edges, nbe, nbr);

    pass1_kernel<<<nt_rad + nt_ang, 256, 0, stream>>>(
        rad_edata, edge_src, ang_angles, angle_src, angle_dst, central_atom,
        cur_rad, cur_ang, arr_rad, arr_ang,
        n_edges, n_pairs, nbkt, nt_rad);

    pass2B_kernel<<<2 * nbkt, 256, 0, stream>>>(
        arr_rad, arr_ang, edata, cur_rad, cur_ang, species, out, nbkt, n_atoms);
}

// Round 19
// 79.307 us; speedup vs baseline: 1.0158x; 1.0158x over previous
//
#include <hip/hip_runtime.h>
#include <hip/hip_fp16.h>
#include <math.h>

// ---- problem constants (match reference) ----
#define NCOLS   407
#define RAD_OFF 87
#define ANG_OFF 151
#define T1      3072          // items per sort tile
#define KPT     (T1 / 256)    // 12 items per thread
#define WB      32            // atoms per bucket (bucket = atom>>5)
#define MAXBKT  640           // max buckets (n_atoms <= 20480)
#define CAPF    1792          // fixed per-bucket region capacity
#define C2      (CAPF / 256)  // 7 items per thread in pass2B

// shiftR[r] = 0.8 + r*0.275  (r=0..15)
// shiftA[a] = 0.8 + a*0.675  (a=0..3)
// shiftZ[z] = pi/8 + z*pi/4  (z=0..3)

typedef __attribute__((ext_vector_type(8))) _Float16 f16x8;
typedef __attribute__((ext_vector_type(4))) float    f32x4;

static __device__ inline unsigned pack2(float a, float b) {
    __half2 h = __floats2half2_rn(a, b);
    return *reinterpret_cast<unsigned*>(&h);
}
static __device__ inline float2 unpack2(unsigned u) {
    __half2 h = *reinterpret_cast<__half2*>(&u);
    return __half22float2(h);
}

// ============ zc: zero slot cursors (tiny) ============
__global__ __launch_bounds__(256) void zc_kernel(int* __restrict__ cursors) {
    int t = threadIdx.x;
    for (int i = t; i < 2 * MAXBKT; i += 256) cursors[i] = 0;
}

// ============ pass1: edata build + records + LDS bucket-reorder + claimed store ============
// blocks [0, nbe): angular edata streaming builders (no LDS use)
// blocks [nbe, nbe+nt_rad): radial sort tiles (records built inline)
// blocks [nbe+nt_rad, nbe+nt_rad+nt_ang): angular sort tiles
// records: radial {d, pv01, pv23, atom}; angular {e1, e2, ang, atom}
__global__ __launch_bounds__(256) void pass1_kernel(
    const float* __restrict__ dist, const float* __restrict__ sw,
    const int* __restrict__ esrc, const int* __restrict__ edst,
    const float* __restrict__ ang_angles,
    const float* __restrict__ ang_dist, const float* __restrict__ ang_sw,
    const int* __restrict__ ang_edge_dst,
    const int* __restrict__ psrc, const int* __restrict__ pdst,
    const int* __restrict__ central,
    const int* __restrict__ species, const float4* __restrict__ valence,
    uint4* __restrict__ edata,
    int* __restrict__ cur_rad, int* __restrict__ cur_ang,
    uint4* __restrict__ arr_rad, uint4* __restrict__ arr_ang,
    int n_edges, int n_pairs, int n_ang_edges,
    int nbkt, int nbe, int nt_rad)
{
    __shared__ uint4 buf[T1];        // 48 KB
    __shared__ int   lh[MAXBKT];     // counts -> packed local bases
    __shared__ int   gb[MAXBKT];     // global positions (region base + claimed run)
    __shared__ int   wtot[4];

    int bid = blockIdx.x;
    int t = threadIdx.x;

    if (bid < nbe) {
        // ---- angular edata builder (streaming, no LDS) ----
        int i = bid * 2560 + t;
        #pragma unroll
        for (int k = 0; k < 10; ++k, i += 256) {
            if (i < n_ang_edges) {
                float4 v = valence[species[ang_edge_dst[i]]];
                uint4 r;
                r.x = __float_as_uint(ang_dist[i]);
                r.y = __float_as_uint(ang_sw[i]);
                r.z = pack2(v.x, v.y);
                r.w = pack2(v.z, v.w);
                edata[i] = r;
            }
        }
        return;
    }

    int sbid = bid - nbe;
    int is_ang = sbid >= nt_rad;
    const int* key = is_ang ? central : esrc;
    int* cursor = is_ang ? cur_ang : cur_rad;
    int n   = is_ang ? n_pairs : n_edges;
    int off = (is_ang ? sbid - nt_rad : sbid) * T1;
    int cnt = min(T1, n - off);
    uint4* arr = is_ang ? arr_ang : arr_rad;

    for (int b = t; b < nbkt; b += 256) lh[b] = 0;
    __syncthreads();

    // loop 1: per-item rank within (tile, bucket)
    int meta[KPT];                   // atom<<12 | rank
    #pragma unroll
    for (int k = 0; k < KPT; ++k) {
        int i = off + k * 256 + t;
        meta[k] = -1;
        if (i < n) {
            int atom = key[i];
            int r = atomicAdd(&lh[atom >> 5], 1);
            meta[k] = (atom << 12) | r;
        }
    }
    __syncthreads();

    // scan + claim: per-wave shuffle scan over bin ranges (2 barriers total)
    {
        int w = t >> 6, lane = t & 63;
        int W4  = (nbkt + 3) >> 2;               // bins per wave
        int wlo = w * W4;
        int whi = min(wlo + W4, nbkt);
        int b0 = wlo + lane * 3;                 // 3 bins per lane (64*3=192 >= W4)
        int c0 = (b0     < whi) ? lh[b0]     : 0;
        int c1 = (b0 + 1 < whi) ? lh[b0 + 1] : 0;
        int c2 = (b0 + 2 < whi) ? lh[b0 + 2] : 0;
        int lsum = c0 + c1 + c2;
        int s = lsum;
        #pragma unroll
        for (int o = 1; o < 64; o <<= 1) {
            int u = __shfl_up(s, o, 64);
            if (lane >= o) s += u;
        }
        int excl = s - lsum;                     // wave-local exclusive base
        // claim global runs (independent of packing)
        if (c0) gb[b0]     = b0       * CAPF + atomicAdd(&cursor[b0],     c0);
        if (c1) gb[b0 + 1] = (b0 + 1) * CAPF + atomicAdd(&cursor[b0 + 1], c1);
        if (c2) gb[b0 + 2] = (b0 + 2) * CAPF + atomicAdd(&cursor[b0 + 2], c2);
        // wave-local packed bases
        if (b0     < whi) lh[b0]     = excl;
        if (b0 + 1 < whi) lh[b0 + 1] = excl + c0;
        if (b0 + 2 < whi) lh[b0 + 2] = excl + c0 + c1;
        if (lane == 63) wtot[w] = s;
        __syncthreads();
        int wbase = 0;
        for (int ww = 0; ww < w; ++ww) wbase += wtot[ww];
        if (wbase) {
            if (b0     < whi) lh[b0]     += wbase;
            if (b0 + 1 < whi) lh[b0 + 1] += wbase;
            if (b0 + 2 < whi) lh[b0 + 2] += wbase;
        }
        __syncthreads();
    }

    // loop 2: build records inline, place into LDS at bucket-packed position
    #pragma unroll
    for (int k = 0; k < KPT; ++k) {
        if (meta[k] < 0) continue;
        int i = off + k * 256 + t;
        int atom = meta[k] >> 12, r = meta[k] & 4095;
        int b = atom >> 5;
        uint4 rec;
        if (!is_ang) {
            float d  = dist[i];                  // coalesced
            float ps = 0.25f * sw[i];            // coalesced
            float4 v = valence[species[edst[i]]];// independent gather chains x12
            rec.x = __float_as_uint(d);
            rec.y = pack2(ps * v.x, ps * v.y);
            rec.z = pack2(ps * v.z, ps * v.w);
            rec.w = (unsigned)atom;
        } else {
            rec.x = (unsigned)psrc[i];
            rec.y = (unsigned)pdst[i];
            rec.z = __float_as_uint(ang_angles[i]);
            rec.w = (unsigned)atom;
        }
        buf[lh[b] + r] = rec;
    }
    __syncthreads();

    // loop 3: coalesced writer; dst recomputed from record atom
    #pragma unroll
    for (int k = 0; k < KPT; ++k) {
        int j = k * 256 + t;
        if (j < cnt) {
            uint4 r = buf[j];
            int b = (int)(r.w >> 5);
            int gpos = gb[b] + (j - lh[b]);           // consecutive within run
            if (gpos < (b + 1) * CAPF) arr[gpos] = r; // overflow drop (P~0)
        }
    }
}

// ============ pass2B: per-bucket LDS sort + per-atom MFMA compute + onehot ============
// blocks [0,nbkt): radial buckets; [nbkt,2nbkt): angular buckets
__global__ __launch_bounds__(256) void pass2B_kernel(
    const uint4* __restrict__ arr_rad, const uint4* __restrict__ arr_ang,
    const uint4* __restrict__ edata,
    const int* __restrict__ cur_rad, const int* __restrict__ cur_ang,
    const int* __restrict__ species,
    float* __restrict__ out, int nbkt, int n_atoms)
{
    __shared__ uint4 buf[CAPF];               // 28.7 KB records
    __shared__ unsigned short ord[CAPF];      //  3.5 KB permutation
    __shared__ int lh[WB];
    __shared__ int sA[WB + 1];
    __shared__ uint4 stg[4][256];             // 16 KB per-wave MFMA staging (angular)

    int bid = blockIdx.x;
    int t = threadIdx.x;
    int g = bid >= nbkt;
    int b = g ? bid - nbkt : bid;
    int lo  = b * CAPF;
    int cnt = min(g ? cur_ang[b] : cur_rad[b], CAPF);
    const uint4* arr = g ? arr_ang : arr_rad;
    int loA = b << 5;

    // ---- load + count + rank in ONE pass (ranks in static regs) ----
    if (t < WB) lh[t] = 0;
    __syncthreads();
    int myar[C2];
    #pragma unroll
    for (int c = 0; c < C2; ++c) {
        int j = c * 256 + t;
        myar[c] = -1;
        if (j < cnt) {
            uint4 r = arr[lo + j];
            buf[j] = r;
            int a = (int)r.w - loA;
            if ((unsigned)a < WB) {
                int rk = atomicAdd(&lh[a], 1);
                myar[c] = (a << 12) | rk;
            }
        }
    }
    __syncthreads();
    // wave 0: 32-bin shuffle scan
    if (t < 64) {
        int v = (t < WB) ? lh[t] : 0;
        int s = v;
        #pragma unroll
        for (int o = 1; o < WB; o <<= 1) {
            int u = __shfl_up(s, o, 64);
            if (t >= o) s += u;
        }
        if (t < WB) sA[t + 1] = s;
        if (t == 0) sA[0] = 0;
    }
    __syncthreads();
    #pragma unroll
    for (int c = 0; c < C2; ++c) {
        if (myar[c] >= 0) {
            int j = c * 256 + t;
            ord[sA[myar[c] >> 12] + (myar[c] & 4095)] = (unsigned short)j;
        }
    }
    __syncthreads();

    int w    = t >> 6;
    int lane = t & 63;
    int m  = lane & 15;
    int g4 = lane >> 4;

    if (g) {
        // ---------------- angular: DENSE staging, masked-MFMA per atom ----------------
        const _Float16* hl = (const _Float16*)stg[w];
        int aw0 = w * 8;
        int R0 = sA[aw0], R1 = sA[aw0 + 8];
        int cur = aw0;                       // current atom (wave-uniform)
        f32x4 acc = {0.f, 0.f, 0.f, 0.f};

        for (int base = R0; base < R1; base += 64) {
            int idx = base + lane;
            unsigned q[16];
            if (idx < R1) {
                uint4 pr = buf[ord[idx]];                 // LDS gather
                int e1 = (int)pr.x;
                int e2 = (int)pr.y;
                float ang = __uint_as_float(pr.z);
                uint4 r1 = edata[e1];                     // L2-hot gathers
                uint4 r2 = edata[e2];
                float d12 = 0.5f * (__uint_as_float(r1.x) + __uint_as_float(r2.x));
                float swp = 2.0f * __uint_as_float(r1.y) * __uint_as_float(r2.y);
                float2 v1a = unpack2(r1.z), v1b = unpack2(r1.w);
                float2 v2a = unpack2(r2.z), v2b = unpack2(r2.w);
                float vp[4] = {v1a.x + v2a.x, v1a.y + v2a.y, v1b.x + v2b.x, v1b.y + v2b.y};
                float vm[4] = {v1a.x * v2a.x, v1a.y * v2a.y, v1b.x * v2b.x, v1b.y * v2b.y};

                float sa, ca;
                __sincosf(ang, &sa, &ca);
                const float czv[4] = { 0.92387953f,  0.38268343f, -0.38268343f, -0.92387953f };
                const float szv[4] = { 0.38268343f,  0.92387953f,  0.92387953f,  0.38268343f };
                float f1v[4];
                #pragma unroll
                for (int z = 0; z < 4; ++z) {
                    float y = 0.5f + 0.5f * (ca * czv[z] + sa * szv[z]);
                    float y2 = y * y, y4 = y2 * y2, y8 = y4 * y4, y16 = y8 * y8;
                    f1v[z] = y16 * y16;
                }
                float f2sv[4];
                #pragma unroll
                for (int aa = 0; aa < 4; ++aa) {
                    float x = d12 - (0.8f + 0.675f * (float)aa);
                    f2sv[aa] = swp * __expf(-8.0f * x * x);
                }
                #pragma unroll
                for (int aa = 0; aa < 4; ++aa) {
                    q[aa * 2 + 0] = pack2(f2sv[aa] * f1v[0], f2sv[aa] * f1v[1]);
                    q[aa * 2 + 1] = pack2(f2sv[aa] * f1v[2], f2sv[aa] * f1v[3]);
                }
                #pragma unroll
                for (int i2 = 0; i2 < 4; ++i2) {
                    q[8 + i2 * 2 + 0] = pack2(vp[i2] * vm[0], vp[i2] * vm[1]);
                    q[8 + i2 * 2 + 1] = pack2(vp[i2] * vm[2], vp[i2] * vm[3]);
                }
            } else {
                #pragma unroll
                for (int k = 0; k < 16; ++k) q[k] = 0u;   // zero-pad tail
            }
            stg[w][lane * 4 + 0] = make_uint4(q[0],  q[1],  q[2],  q[3]);
            stg[w][lane * 4 + 1] = make_uint4(q[4],  q[5],  q[6],  q[7]);
            stg[w][lane * 4 + 2] = make_uint4(q[8],  q[9],  q[10], q[11]);
            stg[w][lane * 4 + 3] = make_uint4(q[12], q[13], q[14], q[15]);
            asm volatile("s_waitcnt lgkmcnt(0)" ::: "memory");

            // consume the two 32-row chunks of this staged block
            #pragma unroll
            for (int c = 0; c < 2; ++c) {
                int cbase = base + c * 32;
                if (cbase >= R1) break;
                while (cur < aw0 + 8) {
                    int abeg = sA[cur], aend = sA[cur + 1];
                    int lo_r = max(abeg, cbase) - cbase;
                    int hi_r = min(aend, cbase + 32) - cbase;
                    if (hi_r > lo_r) {
                        f16x8 wf, uf;
                        #pragma unroll
                        for (int i = 0; i < 8; ++i) {
                            int rr  = (g4 << 3) + i;          // row within chunk (k-slot)
                            int row = c * 32 + rr;            // row within staged block
                            bool live = (rr >= lo_r && rr < hi_r);
                            wf[i] = live ? hl[row * 32 + m] : (_Float16)0.0f;
                            uf[i] = hl[row * 32 + 16 + m];    // wf=0 masks contribution
                        }
                        acc = __builtin_amdgcn_mfma_f32_16x16x32_f16(wf, uf, acc, 0, 0, 0);
                    }
                    if (aend <= cbase + 32) {
                        // atom complete: flush (C/D: col=lane&15, row=(lane>>4)*4+reg)
                        int atom = loA + cur;
                        if (atom < n_atoms) {
                            float* orow = out + (size_t)atom * NCOLS + ANG_OFF;
                            #pragma unroll
                            for (int r = 0; r < 4; ++r)
                                orow[(g4 * 4 + r) * 16 + m] = acc[r];
                        }
                        acc = (f32x4){0.f, 0.f, 0.f, 0.f};
                        ++cur;
                    } else {
                        break;   // atom extends into next chunk
                    }
                }
            }
            asm volatile("s_waitcnt lgkmcnt(0)" ::: "memory");
        }
        // trailing atoms with no pairs (or R0==R1 entirely)
        while (cur < aw0 + 8) {
            int atom = loA + cur;
            if (atom < n_atoms) {
                float* orow = out + (size_t)atom * NCOLS + ANG_OFF;
                #pragma unroll
                for (int r = 0; r < 4; ++r)
                    orow[(g4 * 4 + r) * 16 + m] = 0.0f;
            }
            ++cur;
        }
        return;
    }

    // ---------------- radial: 4 waves x 8 atoms + onehot ----------------
    const _Float16* hl = (const _Float16*)buf;     // rec = 8 halves: [d_lo,d_hi,pv0..3,atom]
    const float*    fl = (const float*)buf;
    float shiftm = 0.8f + 0.275f * (float)m;
    for (int ai = 0; ai < 8; ++ai) {
        int a = w * 8 + ai;
        int atom = loA + a;
        if (atom >= n_atoms) break;
        int beg = sA[a], end = sA[a + 1];
        f32x4 acc = {0.f, 0.f, 0.f, 0.f};

        for (int base = beg; base < end; base += 64) {
            int cnt2 = min(64, end - base);
            {
                f16x8 wf, uf;
                #pragma unroll
                for (int i = 0; i < 8; ++i) {
                    int k = (g4 << 3) + i;                // edges 0..31
                    int live = (k < cnt2);
                    int o = live ? (int)ord[base + k] : 0;
                    float d = fl[o * 4];
                    float x = d - shiftm;
                    float e = __expf(-16.0f * x * x);
                    wf[i] = live ? (_Float16)e : (_Float16)0.0f;
                    uf[i] = (live && m < 4) ? hl[o * 8 + 2 + m] : (_Float16)0.0f;
                }
                acc = __builtin_amdgcn_mfma_f32_16x16x32_f16(wf, uf, acc, 0, 0, 0);
            }
            if (cnt2 > 32) {
                f16x8 wf, uf;
                #pragma unroll
                for (int i = 0; i < 8; ++i) {
                    int k = 32 + (g4 << 3) + i;           // edges 32..63
                    int live = (k < cnt2);
                    int o = live ? (int)ord[base + k] : 0;
                    float d = fl[o * 4];
                    float x = d - shiftm;
                    float e = __expf(-16.0f * x * x);
                    wf[i] = live ? (_Float16)e : (_Float16)0.0f;
                    uf[i] = (live && m < 4) ? hl[o * 8 + 2 + m] : (_Float16)0.0f;
                }
                acc = __builtin_amdgcn_mfma_f32_16x16x32_f16(wf, uf, acc, 0, 0, 0);
            }
        }
        if (m < 4) {
            size_t rowbase = (size_t)atom * NCOLS;
            #pragma unroll
            for (int r = 0; r < 4; ++r)
                out[rowbase + RAD_OFF + (g4 * 4 + r) * 4 + m] = acc[r];
        }
    }

    // onehot for this bucket's 32 atoms
    for (int idx2 = t; idx2 < WB * 87; idx2 += 256) {
        int a = idx2 / 87, c = idx2 - a * 87;
        int atom = loA + a;
        if (atom < n_atoms)
            out[(size_t)atom * NCOLS + c] = (c == species[atom]) ? 1.0f : 0.0f;
    }
}

extern "C" void kernel_launch(void* const* d_in, const int* in_sizes, int n_in,
                              void* d_out, int out_size, void* d_ws, size_t ws_size,
                              hipStream_t stream) {
    const int*   species      = (const int*)  d_in[0];
    const float* distances    = (const float*)d_in[1];
    const float* switch_      = (const float*)d_in[2];
    const int*   edge_src     = (const int*)  d_in[3];
    const int*   edge_dst     = (const int*)  d_in[4];
    const float* ang_angles   = (const float*)d_in[5];
    const float* ang_dist     = (const float*)d_in[6];
    const float* ang_switch   = (const float*)d_in[7];
    const int*   ang_edge_dst = (const int*)  d_in[8];
    const int*   angle_src    = (const int*)  d_in[9];
    const int*   angle_dst    = (const int*)  d_in[10];
    const int*   central_atom = (const int*)  d_in[11];
    const float4* valence     = (const float4*)d_in[12];

    float* out = (float*)d_out;

    const int n_atoms     = in_sizes[0];
    const int n_edges     = in_sizes[1];
    const int n_ang_edges = in_sizes[6];
    const int n_pairs     = in_sizes[5];

    const int nbkt   = (n_atoms + WB - 1) / WB;       // 625 (<= MAXBKT)
    const int nt_rad = (n_edges + T1 - 1) / T1;       // 209
    const int nt_ang = (n_pairs + T1 - 1) / T1;       // 183
    const int nbe    = (n_ang_edges + 2559) / 2560;   // 63

    // ---- workspace layout (16B-aligned), total ~= 38.4 MB ----
    char* ws = (char*)d_ws;
    size_t off = 0;
    auto alloc = [&](size_t bytes) -> void* {
        void* p = ws + off;
        off = (off + bytes + 15) & ~(size_t)15;
        return p;
    };
    uint4* arr_rad = (uint4*)alloc((size_t)nbkt * CAPF * 16);        // 17.92 MB
    uint4* arr_ang = (uint4*)alloc((size_t)nbkt * CAPF * 16);        // 17.92 MB
    uint4* edata   = (uint4*)alloc((size_t)n_ang_edges * 16);        //  2.56 MB
    int*   cursors = (int*)  alloc((size_t)2 * MAXBKT * sizeof(int));
    int* cur_rad = cursors;
    int* cur_ang = cursors + MAXBKT;

    zc_kernel<<<1, 256, 0, stream>>>(cursors);

    pass1_kernel<<<nbe + nt_rad + nt_ang, 256, 0, stream>>>(
        distances, switch_, edge_src, edge_dst,
        ang_angles, ang_dist, ang_switch, ang_edge_dst,
        angle_src, angle_dst, central_atom,
        species, valence, edata,
        cur_rad, cur_ang, arr_rad, arr_ang,
        n_edges, n_pairs, n_ang_edges, nbkt, nbe, nt_rad);

    pass2B_kernel<<<2 * nbkt, 256, 0, stream>>>(
        arr_rad, arr_ang, edata, cur_rad, cur_ang, species, out, nbkt, n_atoms);
}